// Round 13
// baseline (417.104 us; speedup 1.0000x reference)
//
#include <hip/hip_runtime.h>
#include <stdint.h>

typedef short bf16x8 __attribute__((ext_vector_type(8)));
typedef float f32x4 __attribute__((ext_vector_type(4)));
typedef uint32_t u32x4 __attribute__((ext_vector_type(4)));
typedef uint32_t u32x2 __attribute__((ext_vector_type(2)));

__device__ __forceinline__ float bf2f(uint16_t b){
  union { uint32_t u; float f; } v; v.u = ((uint32_t)b) << 16; return v.f;
}
__device__ __forceinline__ float u2f(uint32_t u){
  union { uint32_t u; float f; } v; v.u = u; return v.f;
}
// HW packed f32->bf16 (RNE): lo = bf16(a), hi = bf16(b)
__device__ __forceinline__ uint32_t pk_bf16(float a, float b){
  uint32_t r;
  asm("v_cvt_pk_bf16_f32 %0, %1, %2" : "=v"(r) : "v"(a), "v"(b));
  return r;
}
__device__ __forceinline__ uint16_t f2bf(float f){
  return (uint16_t)pk_bf16(f, f);
}

// async global->LDS, 16B per lane; lds base wave-uniform (HW adds lane*16)
__device__ __forceinline__ void gl2lds16(const uint16_t* g, uint16_t* l) {
  __builtin_amdgcn_global_load_lds((const __attribute__((address_space(1))) void*)g,
                                   (__attribute__((address_space(3))) void*)l, 16, 0, 0);
}

// ---------------- weight transpose + f32->bf16 convert (optional row-scale) ----
__global__ __launch_bounds__(256) void transpose_cvt(
    const float* __restrict__ src, uint16_t* __restrict__ dst, int K, int N,
    const float* __restrict__ scale)
{
  __shared__ float tile[32][33];
  int n0 = blockIdx.x * 32, k0 = blockIdx.y * 32;
  int tx = threadIdx.x & 31, ty = threadIdx.x >> 5;
  #pragma unroll
  for (int i = 0; i < 4; i++) {
    int k = k0 + ty + 8*i;
    float v = src[(size_t)k * N + n0 + tx];
    if (scale) v *= scale[k];
    tile[ty + 8*i][tx] = v;
  }
  __syncthreads();
  #pragma unroll
  for (int i = 0; i < 4; i++)
    dst[(size_t)(n0 + ty + 8*i) * K + k0 + tx] = f2bf(tile[tx][ty + 8*i]);
}

// ---------------- LN1 fold precompute: c1[j]=sum_k g1[k]Wfp[k][j]; b1p=be1@Wfp+bfp ----
__global__ __launch_bounds__(256) void fold_fp(
    const float* __restrict__ Wfp, const float* __restrict__ g1,
    const float* __restrict__ be1, const float* __restrict__ bfp,
    float* __restrict__ c1, float* __restrict__ b1p)
{
  int j = threadIdx.x;
  float c = 0.f, b = 0.f;
  for (int k = 0; k < 256; k++) {
    float w = Wfp[k * 256 + j];
    c += g1[k] * w;
    b += be1[k] * w;
  }
  c1[j] = c;
  b1p[j] = b + bfp[j];
}

// ---------------- fused mid: qkv GEMM + attn(6x6) + LN1(folded) + fp GEMM + LN2 -> F ----
// 512 threads (8 waves), 48 rows; LDS overlay: h lives in dead K|V region of qs.
#define LX 136
#define LQ 392

__global__ __launch_bounds__(512, 4) void fused_mid(
    const float* __restrict__ X, const uint16_t* __restrict__ WqkvT,
    const float* __restrict__ bqkv, const uint16_t* __restrict__ Wfp2T,
    const float* __restrict__ c1, const float* __restrict__ b1p,
    const float* __restrict__ g2, const float* __restrict__ be2,
    uint16_t* __restrict__ F)
{
  __shared__ uint16_t xs[48 * LX];    // 12.75 KB  x bf16
  __shared__ uint16_t qs[48 * LQ];    // 36.75 KB
  __shared__ float    sb[8 * 36];
  __shared__ float    smu[48], srs[48];
  int t = threadIdx.x;
  int lane = t & 63, wave = t >> 6;   // 8 waves
  int lr = lane & 15, lh = lane >> 4;
  size_t r0 = (size_t)blockIdx.x * 48;

  // ---- phase 1: stage x -> xs (bf16, packed cvt) ----
  for (int i = t; i < 768; i += 512) {
    int row = i >> 4, c = (i & 15) * 8;
    const float* g = X + (r0 + row) * 128 + c;
    f32x4 v0 = *(const f32x4*)g, v1 = *(const f32x4*)(g + 4);
    u32x4 o;
    o[0] = pk_bf16(v0[0], v0[1]); o[1] = pk_bf16(v0[2], v0[3]);
    o[2] = pk_bf16(v1[0], v1[1]); o[3] = pk_bf16(v1[2], v1[3]);
    *(u32x4*)(xs + row * LX + c) = o;
  }
  __syncthreads();

  // ---- phase 2: qkv GEMM (48x384), 8 waves x 48 cols ----
  {
    f32x4 acc[3][3] = {};
    #pragma unroll
    for (int k0 = 0; k0 < 128; k0 += 32) {
      bf16x8 af[3], bw[3];
      #pragma unroll
      for (int i = 0; i < 3; i++)
        af[i] = *(const bf16x8*)(xs + (i*16 + lr) * LX + k0 + lh*8);
      #pragma unroll
      for (int j = 0; j < 3; j++)
        bw[j] = *(const bf16x8*)(WqkvT + (size_t)(wave*48 + j*16 + lr) * 128 + k0 + lh*8);
      #pragma unroll
      for (int i = 0; i < 3; i++)
        #pragma unroll
        for (int j = 0; j < 3; j++)
          acc[i][j] = __builtin_amdgcn_mfma_f32_16x16x32_bf16(af[i], bw[j], acc[i][j], 0, 0, 0);
    }
    #pragma unroll
    for (int i = 0; i < 3; i++)
      #pragma unroll
      for (int j = 0; j < 3; j++) {
        int col = wave*48 + j*16 + lr;
        float bv = bqkv[col];
        #pragma unroll
        for (int r = 0; r < 4; r++)
          qs[(i*16 + lh*4 + r) * LQ + col] = f2bf(acc[i][j][r] + bv);
      }
  }
  __syncthreads();

  // ---- phase 3: S[b][q][k] = Q . K  (b128 LDS reads: 32 per dot) ----
  for (int i = t; i < 288; i += 512) {
    int b = i / 36, q = (i / 6) % 6, k = i % 6;
    const uint16_t* Qr = qs + (b*6 + q) * LQ;
    const uint16_t* Kr = qs + (b*6 + k) * LQ + 128;
    float s = 0.f;
    #pragma unroll
    for (int d = 0; d < 16; d++) {
      u32x4 qv = *(const u32x4*)(Qr + d*8);
      u32x4 kv = *(const u32x4*)(Kr + d*8);
      #pragma unroll
      for (int j = 0; j < 4; j++) {
        s += u2f(qv[j] << 16) * u2f(kv[j] << 16)
           + u2f(qv[j] & 0xFFFF0000u) * u2f(kv[j] & 0xFFFF0000u);
      }
    }
    sb[i] = s;
  }
  __syncthreads();

  // ---- phase 4: ar = S @ V -> dead Q region (u32x2 reads/writes) ----
  for (int i = t; i < 1536; i += 512) {
    int r = i >> 5, dp = (i & 31) * 2;   // dp = u32 pair index (4 bf16)
    int b = r / 6;
    const float* sr = sb + b*36 + (r - b*6)*6;
    float a0 = 0.f, a1 = 0.f, a2 = 0.f, a3 = 0.f;
    #pragma unroll
    for (int k = 0; k < 6; k++) {
      u32x2 vu = *(const u32x2*)(qs + (b*6 + k)*LQ + 256 + dp*2);
      float sk = sr[k];
      a0 += sk * u2f(vu[0] << 16);
      a1 += sk * u2f(vu[0] & 0xFFFF0000u);
      a2 += sk * u2f(vu[1] << 16);
      a3 += sk * u2f(vu[1] & 0xFFFF0000u);
    }
    u32x2 o; o[0] = pk_bf16(a0, a1); o[1] = pk_bf16(a2, a3);
    *(u32x2*)((uint32_t*)(qs + r*LQ) + dp) = o;
  }
  __syncthreads();

  // ---- phase 5: [t<192] LN1 stats; ALL: fp GEMM (8 waves x 32 cols) ----
  if (t < 192) {
    int r = t >> 2, p = t & 3;
    const uint32_t* src = (p < 2) ? (const uint32_t*)(xs + r*LX + p*64)
                                  : (const uint32_t*)(qs + r*LQ + (p - 2)*64);
    float s1 = 0.f, s2 = 0.f;
    #pragma unroll 8
    for (int d = 0; d < 32; d++) {
      uint32_t u = src[d];
      float a = u2f(u << 16), b = u2f(u & 0xFFFF0000u);
      s1 += a + b; s2 += a*a + b*b;
    }
    s1 += __shfl_xor(s1, 1); s2 += __shfl_xor(s2, 1);
    s1 += __shfl_xor(s1, 2); s2 += __shfl_xor(s2, 2);
    float mu = s1 * (1.f/256.f);
    float var = s2 * (1.f/256.f) - mu*mu;
    if (p == 0) { smu[r] = mu; srs[r] = rsqrtf(var + 1e-5f); }
  }
  f32x4 acc2[3][2] = {};
  #pragma unroll
  for (int k0 = 0; k0 < 256; k0 += 32) {
    bf16x8 af[3], bw[2];
    #pragma unroll
    for (int i = 0; i < 3; i++) {
      const uint16_t* mrow = (k0 < 128) ? (xs + (i*16 + lr) * LX + k0)
                                        : (qs + (i*16 + lr) * LQ + (k0 - 128));
      af[i] = *(const bf16x8*)(mrow + lh*8);
    }
    #pragma unroll
    for (int j = 0; j < 2; j++)
      bw[j] = *(const bf16x8*)(Wfp2T + (size_t)(wave*32 + j*16 + lr) * 256 + k0 + lh*8);
    #pragma unroll
    for (int i = 0; i < 3; i++)
      #pragma unroll
      for (int j = 0; j < 2; j++)
        acc2[i][j] = __builtin_amdgcn_mfma_f32_16x16x32_bf16(af[i], bw[j], acc2[i][j], 0, 0, 0);
  }
  __syncthreads();

  // ---- phase 6: h = rs1*(G - mu1*c1[col]) + b1p[col] -> qs[.,128+col] ----
  #pragma unroll
  for (int i = 0; i < 3; i++)
    #pragma unroll
    for (int j = 0; j < 2; j++) {
      int col = wave*32 + j*16 + lr;
      float c1v = c1[col], b1v = b1p[col];
      #pragma unroll
      for (int r = 0; r < 4; r++) {
        int row = i*16 + lh*4 + r;
        float h = srs[row] * (acc2[i][j][r] - smu[row] * c1v) + b1v;
        qs[row * LQ + 128 + col] = f2bf(h);
      }
    }
  __syncthreads();

  // ---- phase 7: LN2 stats over [h(256) | x(128) | ar(128)] ----
  if (t < 192) {
    int r = t >> 2, p = t & 3;
    const uint32_t* src = (p < 2) ? (const uint32_t*)(qs + r*LQ + 128 + p*128)
                        : (p == 2) ? (const uint32_t*)(xs + r*LX)
                                   : (const uint32_t*)(qs + r*LQ);
    float s1 = 0.f, s2 = 0.f;
    #pragma unroll 8
    for (int d = 0; d < 64; d++) {
      uint32_t u = src[d];
      float a = u2f(u << 16), b = u2f(u & 0xFFFF0000u);
      s1 += a + b; s2 += a*a + b*b;
    }
    s1 += __shfl_xor(s1, 1); s2 += __shfl_xor(s2, 1);
    s1 += __shfl_xor(s1, 2); s2 += __shfl_xor(s2, 2);
    float mu = s1 * (1.f/512.f);
    float var = s2 * (1.f/512.f) - mu*mu;
    if (p == 0) { smu[r] = mu; srs[r] = rsqrtf(var + 1e-5f); }
  }
  __syncthreads();

  // ---- phase 8: f = LN2([h|x|ar]) -> F (packed cvt) ----
  for (int i = t; i < 3072; i += 512) {
    int r = i >> 6, c0 = (i & 63) * 8;
    float mu = smu[r], rs = srs[r];
    const uint16_t* src = (c0 < 256) ? (qs + r*LQ + 128 + c0)
                        : (c0 < 384) ? (xs + r*LX + (c0 - 256))
                                     : (qs + r*LQ + (c0 - 384));
    bf16x8 v = *(const bf16x8*)src;
    f32x4 gv0 = *(const f32x4*)(g2 + c0), gv1 = *(const f32x4*)(g2 + c0 + 4);
    f32x4 bv0 = *(const f32x4*)(be2 + c0), bv1 = *(const f32x4*)(be2 + c0 + 4);
    float f[8];
    #pragma unroll
    for (int j = 0; j < 4; j++) {
      f[j]   = (bf2f((uint16_t)v[j])   - mu) * rs * gv0[j] + bv0[j];
      f[4+j] = (bf2f((uint16_t)v[4+j]) - mu) * rs * gv1[j] + bv1[j];
    }
    u32x4 o;
    o[0] = pk_bf16(f[0], f[1]); o[1] = pk_bf16(f[2], f[3]);
    o[2] = pk_bf16(f[4], f[5]); o[3] = pk_bf16(f[6], f[7]);
    *(u32x4*)(F + (r0 + r) * 512 + c0) = o;
  }
}

// ---------------- K4: out = relu(f @ W_s + b_s) ----------------
// 256x256, 8 waves, BK=32, 2-slot ring (64KB -> 2 blocks/CU), m97-style
// full-drain gate; inter-block overlap hides the drain. Chunk-XOR swizzle.
__global__ __launch_bounds__(512, 2) void out_gemm(
    const uint16_t* __restrict__ F, const uint16_t* __restrict__ WsT,
    const float* __restrict__ b_s, float* __restrict__ OUT)
{
  __shared__ uint16_t lds[2][2][256*32];   // 64 KB
  int t = threadIdx.x;
  int lane = t & 63, wave = t >> 6;
  int wm = wave >> 2, wn = wave & 3;
  int lr = lane & 15, lh = lane >> 4;

  int bid = blockIdx.x;
  int swz = (bid & 7) * 64 + (bid >> 3);
  size_t m0 = (size_t)(swz >> 2) * 256;
  int n0 = (swz & 3) * 256;

  int srow = t >> 2;
  int gch  = (t & 3) ^ ((t >> 3) & 3);
  const uint16_t* Ag = F   + (m0 + srow) * 3072 + gch * 8;
  const uint16_t* Bg = WsT + (size_t)(n0 + srow) * 3072 + gch * 8;

#define STAGE(s, tt) do {                                                    \
    int kk0 = (tt) * 32;                                                     \
    uint16_t* la = &lds[s][0][0];                                            \
    uint16_t* lb = &lds[s][1][0];                                            \
    gl2lds16(Ag + kk0,                    la + wave*512);                    \
    gl2lds16(Ag + (size_t)128*3072 + kk0, la + 4096 + wave*512);             \
    gl2lds16(Bg + kk0,                    lb + wave*512);                    \
    gl2lds16(Bg + (size_t)128*3072 + kk0, lb + 4096 + wave*512);             \
  } while(0)

  f32x4 acc[8][4] = {};
  int swch = (lh ^ ((lr >> 1) & 3)) * 8;

#define COMPUTE(s) do {                                                      \
    const uint16_t* As_ = &lds[s][0][0];                                     \
    const uint16_t* Bs_ = &lds[s][1][0];                                     \
    bf16x8 af[8], bfr[4];                                                    \
    _Pragma("unroll")                                                        \
    for (int i = 0; i < 8; i++)                                              \
      af[i]  = *(const bf16x8*)(As_ + (wm*128 + i*16 + lr)*32 + swch);       \
    _Pragma("unroll")                                                        \
    for (int j = 0; j < 4; j++)                                              \
      bfr[j] = *(const bf16x8*)(Bs_ + (wn*64 + j*16 + lr)*32 + swch);        \
    __builtin_amdgcn_s_setprio(1);                                           \
    _Pragma("unroll")                                                        \
    for (int i = 0; i < 8; i++)                                              \
      _Pragma("unroll")                                                      \
      for (int j = 0; j < 4; j++)                                            \
        acc[i][j] = __builtin_amdgcn_mfma_f32_16x16x32_bf16(af[i], bfr[j],   \
                                                            acc[i][j],0,0,0);\
    __builtin_amdgcn_s_setprio(0);                                           \
  } while(0)

  STAGE(0, 0);
  for (int tt = 0; tt < 96; ++tt) {
    int cur = tt & 1;
    asm volatile("s_waitcnt vmcnt(0)" ::: "memory");   // tile tt landed (all waves after barrier)
    __builtin_amdgcn_s_barrier();                      // slot cur^1 readers done
    asm volatile("" ::: "memory");
    if (tt < 95) STAGE(cur ^ 1, tt + 1);               // overwrite freed slot
    COMPUTE(cur);
  }

#undef STAGE
#undef COMPUTE

  #pragma unroll
  for (int i = 0; i < 8; i++)
    #pragma unroll
    for (int j = 0; j < 4; j++) {
      int col = n0 + wn*64 + j*16 + lr;
      float bv = b_s[col];
      #pragma unroll
      for (int r = 0; r < 4; r++) {
        size_t row = m0 + wm*128 + i*16 + lh*4 + r;
        OUT[row * 1024 + col] = fmaxf(acc[i][j][r] + bv, 0.f);
      }
    }
}

extern "C" void kernel_launch(void* const* d_in, const int* in_sizes, int n_in,
                              void* d_out, int out_size, void* d_ws, size_t ws_size,
                              hipStream_t stream) {
  const float* x    = (const float*)d_in[0];
  const float* Wqkv = (const float*)d_in[1];
  const float* bqkv = (const float*)d_in[2];
  const float* g1   = (const float*)d_in[3];
  const float* be1  = (const float*)d_in[4];
  const float* Wfp  = (const float*)d_in[5];
  const float* bfp  = (const float*)d_in[6];
  const float* g2   = (const float*)d_in[7];
  const float* be2  = (const float*)d_in[8];
  const float* Ws   = (const float*)d_in[9];
  const float* bs   = (const float*)d_in[10];
  float* out = (float*)d_out;

  uint8_t* ws = (uint8_t*)d_ws;
  uint16_t* F     = (uint16_t*)(ws);                  // 32768x3072 bf16
  uint16_t* WqkvT = (uint16_t*)(ws + 201326592ull);   // 384x128
  uint16_t* Wfp2T = (uint16_t*)(ws + 201424896ull);   // 256x256 (g1-folded)
  uint16_t* WsT   = (uint16_t*)(ws + 201555968ull);   // 1024x3072
  float*    c1    = (float*)(ws + 207847424ull);      // 256 f32
  float*    b1p   = (float*)(ws + 207848448ull);      // 256 f32

  transpose_cvt<<<dim3(12, 4), 256, 0, stream>>>(Wqkv, WqkvT, 128, 384, nullptr);
  transpose_cvt<<<dim3(8, 8), 256, 0, stream>>>(Wfp, Wfp2T, 256, 256, g1);
  transpose_cvt<<<dim3(32, 96), 256, 0, stream>>>(Ws, WsT, 3072, 1024, nullptr);
  fold_fp<<<dim3(1), 256, 0, stream>>>(Wfp, g1, be1, bfp, c1, b1p);
  fused_mid<<<dim3(4096), 512, 0, stream>>>(x, WqkvT, bqkv, Wfp2T, c1, b1p,
                                            g2, be2, F);
  out_gemm<<<dim3(512), 512, 0, stream>>>(F, WsT, bs, out);
}

// Round 14
// 400.267 us; speedup vs baseline: 1.0421x; 1.0421x over previous
//
#include <hip/hip_runtime.h>
#include <stdint.h>

typedef short bf16x8 __attribute__((ext_vector_type(8)));
typedef float f32x4 __attribute__((ext_vector_type(4)));
typedef uint32_t u32x4 __attribute__((ext_vector_type(4)));
typedef uint32_t u32x2 __attribute__((ext_vector_type(2)));

__device__ __forceinline__ float bf2f(uint16_t b){
  union { uint32_t u; float f; } v; v.u = ((uint32_t)b) << 16; return v.f;
}
__device__ __forceinline__ float u2f(uint32_t u){
  union { uint32_t u; float f; } v; v.u = u; return v.f;
}
// HW packed f32->bf16 (RNE): lo = bf16(a), hi = bf16(b)
__device__ __forceinline__ uint32_t pk_bf16(float a, float b){
  uint32_t r;
  asm("v_cvt_pk_bf16_f32 %0, %1, %2" : "=v"(r) : "v"(a), "v"(b));
  return r;
}
__device__ __forceinline__ uint16_t f2bf(float f){
  return (uint16_t)pk_bf16(f, f);
}

// async global->LDS, 16B per lane; lds base wave-uniform (HW adds lane*16)
__device__ __forceinline__ void gl2lds16(const uint16_t* g, uint16_t* l) {
  __builtin_amdgcn_global_load_lds((const __attribute__((address_space(1))) void*)g,
                                   (__attribute__((address_space(3))) void*)l, 16, 0, 0);
}

// ---------------- weight transpose + f32->bf16 convert (optional row-scale) ----
__global__ __launch_bounds__(256) void transpose_cvt(
    const float* __restrict__ src, uint16_t* __restrict__ dst, int K, int N,
    const float* __restrict__ scale)
{
  __shared__ float tile[32][33];
  int n0 = blockIdx.x * 32, k0 = blockIdx.y * 32;
  int tx = threadIdx.x & 31, ty = threadIdx.x >> 5;
  #pragma unroll
  for (int i = 0; i < 4; i++) {
    int k = k0 + ty + 8*i;
    float v = src[(size_t)k * N + n0 + tx];
    if (scale) v *= scale[k];
    tile[ty + 8*i][tx] = v;
  }
  __syncthreads();
  #pragma unroll
  for (int i = 0; i < 4; i++)
    dst[(size_t)(n0 + ty + 8*i) * K + k0 + tx] = f2bf(tile[tx][ty + 8*i]);
}

// ---------------- LN1 fold precompute: c1[j]=sum_k g1[k]Wfp[k][j]; b1p=be1@Wfp+bfp ----
__global__ __launch_bounds__(256) void fold_fp(
    const float* __restrict__ Wfp, const float* __restrict__ g1,
    const float* __restrict__ be1, const float* __restrict__ bfp,
    float* __restrict__ c1, float* __restrict__ b1p)
{
  int j = threadIdx.x;
  float c = 0.f, b = 0.f;
  for (int k = 0; k < 256; k++) {
    float w = Wfp[k * 256 + j];
    c += g1[k] * w;
    b += be1[k] * w;
  }
  c1[j] = c;
  b1p[j] = b + bfp[j];
}

// ---------------- fused mid: qkv GEMM + attn(6x6) + LN1(folded) + fp GEMM + LN2 -> F ----
// 512 threads (8 waves), 48 rows; LDS overlay: h lives in dead K|V region of qs.
#define LX 136
#define LQ 392

__global__ __launch_bounds__(512, 4) void fused_mid(
    const float* __restrict__ X, const uint16_t* __restrict__ WqkvT,
    const float* __restrict__ bqkv, const uint16_t* __restrict__ Wfp2T,
    const float* __restrict__ c1, const float* __restrict__ b1p,
    const float* __restrict__ g2, const float* __restrict__ be2,
    uint16_t* __restrict__ F)
{
  __shared__ uint16_t xs[48 * LX];    // 12.75 KB  x bf16
  __shared__ uint16_t qs[48 * LQ];    // 36.75 KB
  __shared__ float    sb[8 * 36];
  __shared__ float    smu[48], srs[48];
  int t = threadIdx.x;
  int lane = t & 63, wave = t >> 6;   // 8 waves
  int lr = lane & 15, lh = lane >> 4;
  size_t r0 = (size_t)blockIdx.x * 48;

  // ---- phase 1: stage x -> xs (bf16, packed cvt) ----
  for (int i = t; i < 768; i += 512) {
    int row = i >> 4, c = (i & 15) * 8;
    const float* g = X + (r0 + row) * 128 + c;
    f32x4 v0 = *(const f32x4*)g, v1 = *(const f32x4*)(g + 4);
    u32x4 o;
    o[0] = pk_bf16(v0[0], v0[1]); o[1] = pk_bf16(v0[2], v0[3]);
    o[2] = pk_bf16(v1[0], v1[1]); o[3] = pk_bf16(v1[2], v1[3]);
    *(u32x4*)(xs + row * LX + c) = o;
  }
  __syncthreads();

  // ---- phase 2: qkv GEMM (48x384), 8 waves x 48 cols ----
  {
    f32x4 acc[3][3] = {};
    #pragma unroll
    for (int k0 = 0; k0 < 128; k0 += 32) {
      bf16x8 af[3], bw[3];
      #pragma unroll
      for (int i = 0; i < 3; i++)
        af[i] = *(const bf16x8*)(xs + (i*16 + lr) * LX + k0 + lh*8);
      #pragma unroll
      for (int j = 0; j < 3; j++)
        bw[j] = *(const bf16x8*)(WqkvT + (size_t)(wave*48 + j*16 + lr) * 128 + k0 + lh*8);
      #pragma unroll
      for (int i = 0; i < 3; i++)
        #pragma unroll
        for (int j = 0; j < 3; j++)
          acc[i][j] = __builtin_amdgcn_mfma_f32_16x16x32_bf16(af[i], bw[j], acc[i][j], 0, 0, 0);
    }
    #pragma unroll
    for (int i = 0; i < 3; i++)
      #pragma unroll
      for (int j = 0; j < 3; j++) {
        int col = wave*48 + j*16 + lr;
        float bv = bqkv[col];
        #pragma unroll
        for (int r = 0; r < 4; r++)
          qs[(i*16 + lh*4 + r) * LQ + col] = f2bf(acc[i][j][r] + bv);
      }
  }
  __syncthreads();

  // ---- phase 3: S[b][q][k] = Q . K  (b128 LDS reads: 32 per dot) ----
  for (int i = t; i < 288; i += 512) {
    int b = i / 36, q = (i / 6) % 6, k = i % 6;
    const uint16_t* Qr = qs + (b*6 + q) * LQ;
    const uint16_t* Kr = qs + (b*6 + k) * LQ + 128;
    float s = 0.f;
    #pragma unroll
    for (int d = 0; d < 16; d++) {
      u32x4 qv = *(const u32x4*)(Qr + d*8);
      u32x4 kv = *(const u32x4*)(Kr + d*8);
      #pragma unroll
      for (int j = 0; j < 4; j++) {
        s += u2f(qv[j] << 16) * u2f(kv[j] << 16)
           + u2f(qv[j] & 0xFFFF0000u) * u2f(kv[j] & 0xFFFF0000u);
      }
    }
    sb[i] = s;
  }
  __syncthreads();

  // ---- phase 4: ar = S @ V -> dead Q region (u32x2 reads/writes) ----
  for (int i = t; i < 1536; i += 512) {
    int r = i >> 5, dp = (i & 31) * 2;   // dp = u32 pair index (4 bf16)
    int b = r / 6;
    const float* sr = sb + b*36 + (r - b*6)*6;
    float a0 = 0.f, a1 = 0.f, a2 = 0.f, a3 = 0.f;
    #pragma unroll
    for (int k = 0; k < 6; k++) {
      u32x2 vu = *(const u32x2*)(qs + (b*6 + k)*LQ + 256 + dp*2);
      float sk = sr[k];
      a0 += sk * u2f(vu[0] << 16);
      a1 += sk * u2f(vu[0] & 0xFFFF0000u);
      a2 += sk * u2f(vu[1] << 16);
      a3 += sk * u2f(vu[1] & 0xFFFF0000u);
    }
    u32x2 o; o[0] = pk_bf16(a0, a1); o[1] = pk_bf16(a2, a3);
    *(u32x2*)((uint32_t*)(qs + r*LQ) + dp) = o;
  }
  __syncthreads();

  // ---- phase 5: [t<192] LN1 stats; ALL: fp GEMM (8 waves x 32 cols) ----
  if (t < 192) {
    int r = t >> 2, p = t & 3;
    const uint32_t* src = (p < 2) ? (const uint32_t*)(xs + r*LX + p*64)
                                  : (const uint32_t*)(qs + r*LQ + (p - 2)*64);
    float s1 = 0.f, s2 = 0.f;
    #pragma unroll 8
    for (int d = 0; d < 32; d++) {
      uint32_t u = src[d];
      float a = u2f(u << 16), b = u2f(u & 0xFFFF0000u);
      s1 += a + b; s2 += a*a + b*b;
    }
    s1 += __shfl_xor(s1, 1); s2 += __shfl_xor(s2, 1);
    s1 += __shfl_xor(s1, 2); s2 += __shfl_xor(s2, 2);
    float mu = s1 * (1.f/256.f);
    float var = s2 * (1.f/256.f) - mu*mu;
    if (p == 0) { smu[r] = mu; srs[r] = rsqrtf(var + 1e-5f); }
  }
  f32x4 acc2[3][2] = {};
  #pragma unroll
  for (int k0 = 0; k0 < 256; k0 += 32) {
    bf16x8 af[3], bw[2];
    #pragma unroll
    for (int i = 0; i < 3; i++) {
      const uint16_t* mrow = (k0 < 128) ? (xs + (i*16 + lr) * LX + k0)
                                        : (qs + (i*16 + lr) * LQ + (k0 - 128));
      af[i] = *(const bf16x8*)(mrow + lh*8);
    }
    #pragma unroll
    for (int j = 0; j < 2; j++)
      bw[j] = *(const bf16x8*)(Wfp2T + (size_t)(wave*32 + j*16 + lr) * 256 + k0 + lh*8);
    #pragma unroll
    for (int i = 0; i < 3; i++)
      #pragma unroll
      for (int j = 0; j < 2; j++)
        acc2[i][j] = __builtin_amdgcn_mfma_f32_16x16x32_bf16(af[i], bw[j], acc2[i][j], 0, 0, 0);
  }
  __syncthreads();

  // ---- phase 6: h = rs1*(G - mu1*c1[col]) + b1p[col] -> qs[.,128+col] ----
  #pragma unroll
  for (int i = 0; i < 3; i++)
    #pragma unroll
    for (int j = 0; j < 2; j++) {
      int col = wave*32 + j*16 + lr;
      float c1v = c1[col], b1v = b1p[col];
      #pragma unroll
      for (int r = 0; r < 4; r++) {
        int row = i*16 + lh*4 + r;
        float h = srs[row] * (acc2[i][j][r] - smu[row] * c1v) + b1v;
        qs[row * LQ + 128 + col] = f2bf(h);
      }
    }
  __syncthreads();

  // ---- phase 7: LN2 stats over [h(256) | x(128) | ar(128)] ----
  if (t < 192) {
    int r = t >> 2, p = t & 3;
    const uint32_t* src = (p < 2) ? (const uint32_t*)(qs + r*LQ + 128 + p*128)
                        : (p == 2) ? (const uint32_t*)(xs + r*LX)
                                   : (const uint32_t*)(qs + r*LQ);
    float s1 = 0.f, s2 = 0.f;
    #pragma unroll 8
    for (int d = 0; d < 64; d++) {
      uint32_t u = src[d];
      float a = u2f(u << 16), b = u2f(u & 0xFFFF0000u);
      s1 += a + b; s2 += a*a + b*b;
    }
    s1 += __shfl_xor(s1, 1); s2 += __shfl_xor(s2, 1);
    s1 += __shfl_xor(s1, 2); s2 += __shfl_xor(s2, 2);
    float mu = s1 * (1.f/512.f);
    float var = s2 * (1.f/512.f) - mu*mu;
    if (p == 0) { smu[r] = mu; srs[r] = rsqrtf(var + 1e-5f); }
  }
  __syncthreads();

  // ---- phase 8: f = LN2([h|x|ar]) -> F (packed cvt) ----
  for (int i = t; i < 3072; i += 512) {
    int r = i >> 6, c0 = (i & 63) * 8;
    float mu = smu[r], rs = srs[r];
    const uint16_t* src = (c0 < 256) ? (qs + r*LQ + 128 + c0)
                        : (c0 < 384) ? (xs + r*LX + (c0 - 256))
                                     : (qs + r*LQ + (c0 - 384));
    bf16x8 v = *(const bf16x8*)src;
    f32x4 gv0 = *(const f32x4*)(g2 + c0), gv1 = *(const f32x4*)(g2 + c0 + 4);
    f32x4 bv0 = *(const f32x4*)(be2 + c0), bv1 = *(const f32x4*)(be2 + c0 + 4);
    float f[8];
    #pragma unroll
    for (int j = 0; j < 4; j++) {
      f[j]   = (bf2f((uint16_t)v[j])   - mu) * rs * gv0[j] + bv0[j];
      f[4+j] = (bf2f((uint16_t)v[4+j]) - mu) * rs * gv1[j] + bv1[j];
    }
    u32x4 o;
    o[0] = pk_bf16(f[0], f[1]); o[1] = pk_bf16(f[2], f[3]);
    o[2] = pk_bf16(f[4], f[5]); o[3] = pk_bf16(f[6], f[7]);
    *(u32x4*)(F + (r0 + r) * 512 + c0) = o;
  }
}

// ---------------- K4: out = relu(f @ W_s + b_s) ----------------
// 256x256, 8 waves, BK=64, 2-slot double buffer (128KB), full-drain gate
// once per 64 K-elems (48 gates), 64 MFMA/wave per gate, row-XOR chunk
// swizzle for 64-elem rows (bank = f(chunk) only; swizzle spreads 16 lanes
// over 8 chunks x 4 banks = 2 lanes/bank).
__global__ __launch_bounds__(512, 2) void out_gemm(
    const uint16_t* __restrict__ F, const uint16_t* __restrict__ WsT,
    const float* __restrict__ b_s, float* __restrict__ OUT)
{
  __shared__ uint16_t lds[2][2][256*64];   // 128 KB: [slot][A/B][row*64 + ch*8]
  int t = threadIdx.x;
  int lane = t & 63, wave = t >> 6;
  int wm = wave >> 2, wn = wave & 3;       // 2m x 4n wave grid
  int lr = lane & 15, lh = lane >> 4;

  int bid = blockIdx.x;
  int swz = (bid & 7) * 64 + (bid >> 3);
  size_t m0 = (size_t)(swz >> 2) * 256;
  int n0 = (swz & 3) * 256;

  // staging: per issue 512 threads cover 64 rows x 64 cols; thread row = t>>3,
  // store chunk = t&7 at LDS (linear dest), global source chunk pre-swizzled
  // gch = (t&7) ^ (row&7) so LDS holds ch' = orig_ch ^ (row&7).
  int srow = t >> 3;                       // 0..63
  int gch  = (t & 7) ^ ((t >> 3) & 7);
  const uint16_t* Ag = F   + (m0 + srow) * 3072 + gch * 8;
  const uint16_t* Bg = WsT + (size_t)(n0 + srow) * 3072 + gch * 8;

#define STAGE(s, tt) do {                                                    \
    int kk0 = (tt) * 64;                                                     \
    uint16_t* la = &lds[s][0][0];                                            \
    uint16_t* lb = &lds[s][1][0];                                            \
    _Pragma("unroll")                                                        \
    for (int is = 0; is < 4; is++) {                                         \
      gl2lds16(Ag + (size_t)(is*64)*3072 + kk0, la + is*4096 + wave*512);    \
      gl2lds16(Bg + (size_t)(is*64)*3072 + kk0, lb + is*4096 + wave*512);    \
    }                                                                        \
  } while(0)

  f32x4 acc[8][4] = {};
  int swlo = lr & 7;                       // row&7 for all fragment rows

#define COMPUTE(s) do {                                                      \
    const uint16_t* As_ = &lds[s][0][0];                                     \
    const uint16_t* Bs_ = &lds[s][1][0];                                     \
    _Pragma("unroll")                                                        \
    for (int ks = 0; ks < 2; ks++) {                                         \
      int ch = ((ks*4 + lh) ^ swlo) * 8;                                     \
      bf16x8 af[8], bfr[4];                                                  \
      _Pragma("unroll")                                                      \
      for (int i = 0; i < 8; i++)                                            \
        af[i]  = *(const bf16x8*)(As_ + (wm*128 + i*16 + lr)*64 + ch);       \
      _Pragma("unroll")                                                      \
      for (int j = 0; j < 4; j++)                                            \
        bfr[j] = *(const bf16x8*)(Bs_ + (wn*64 + j*16 + lr)*64 + ch);        \
      __builtin_amdgcn_s_setprio(1);                                         \
      _Pragma("unroll")                                                      \
      for (int i = 0; i < 8; i++)                                            \
        _Pragma("unroll")                                                    \
        for (int j = 0; j < 4; j++)                                          \
          acc[i][j] = __builtin_amdgcn_mfma_f32_16x16x32_bf16(af[i], bfr[j], \
                                                              acc[i][j],0,0,0);\
      __builtin_amdgcn_s_setprio(0);                                         \
    }                                                                        \
  } while(0)

  STAGE(0, 0);
  for (int tt = 0; tt < 48; ++tt) {
    int cur = tt & 1;
    asm volatile("s_waitcnt vmcnt(0)" ::: "memory");   // tile tt landed
    __builtin_amdgcn_s_barrier();                      // slot cur^1 readers done
    asm volatile("" ::: "memory");
    if (tt < 47) STAGE(cur ^ 1, tt + 1);               // overwrite freed slot
    COMPUTE(cur);
  }

#undef STAGE
#undef COMPUTE

  #pragma unroll
  for (int i = 0; i < 8; i++)
    #pragma unroll
    for (int j = 0; j < 4; j++) {
      int col = n0 + wn*64 + j*16 + lr;
      float bv = b_s[col];
      #pragma unroll
      for (int r = 0; r < 4; r++) {
        size_t row = m0 + wm*128 + i*16 + lh*4 + r;
        OUT[row * 1024 + col] = fmaxf(acc[i][j][r] + bv, 0.f);
      }
    }
}

extern "C" void kernel_launch(void* const* d_in, const int* in_sizes, int n_in,
                              void* d_out, int out_size, void* d_ws, size_t ws_size,
                              hipStream_t stream) {
  const float* x    = (const float*)d_in[0];
  const float* Wqkv = (const float*)d_in[1];
  const float* bqkv = (const float*)d_in[2];
  const float* g1   = (const float*)d_in[3];
  const float* be1  = (const float*)d_in[4];
  const float* Wfp  = (const float*)d_in[5];
  const float* bfp  = (const float*)d_in[6];
  const float* g2   = (const float*)d_in[7];
  const float* be2  = (const float*)d_in[8];
  const float* Ws   = (const float*)d_in[9];
  const float* bs   = (const float*)d_in[10];
  float* out = (float*)d_out;

  uint8_t* ws = (uint8_t*)d_ws;
  uint16_t* F     = (uint16_t*)(ws);                  // 32768x3072 bf16
  uint16_t* WqkvT = (uint16_t*)(ws + 201326592ull);   // 384x128
  uint16_t* Wfp2T = (uint16_t*)(ws + 201424896ull);   // 256x256 (g1-folded)
  uint16_t* WsT   = (uint16_t*)(ws + 201555968ull);   // 1024x3072
  float*    c1    = (float*)(ws + 207847424ull);      // 256 f32
  float*    b1p   = (float*)(ws + 207848448ull);      // 256 f32

  transpose_cvt<<<dim3(12, 4), 256, 0, stream>>>(Wqkv, WqkvT, 128, 384, nullptr);
  transpose_cvt<<<dim3(8, 8), 256, 0, stream>>>(Wfp, Wfp2T, 256, 256, g1);
  transpose_cvt<<<dim3(32, 96), 256, 0, stream>>>(Ws, WsT, 3072, 1024, nullptr);
  fold_fp<<<dim3(1), 256, 0, stream>>>(Wfp, g1, be1, bfp, c1, b1p);
  fused_mid<<<dim3(4096), 512, 0, stream>>>(x, WqkvT, bqkv, Wfp2T, c1, b1p,
                                            g2, be2, F);
  out_gemm<<<dim3(512), 512, 0, stream>>>(F, WsT, bs, out);
}

// Round 15
// 396.811 us; speedup vs baseline: 1.0511x; 1.0087x over previous
//
#include <hip/hip_runtime.h>
#include <stdint.h>

typedef short bf16x8 __attribute__((ext_vector_type(8)));
typedef float f32x4 __attribute__((ext_vector_type(4)));
typedef uint32_t u32x4 __attribute__((ext_vector_type(4)));
typedef uint32_t u32x2 __attribute__((ext_vector_type(2)));

__device__ __forceinline__ float bf2f(uint16_t b){
  union { uint32_t u; float f; } v; v.u = ((uint32_t)b) << 16; return v.f;
}
__device__ __forceinline__ float u2f(uint32_t u){
  union { uint32_t u; float f; } v; v.u = u; return v.f;
}
// HW packed f32->bf16 (RNE): lo = bf16(a), hi = bf16(b)
__device__ __forceinline__ uint32_t pk_bf16(float a, float b){
  uint32_t r;
  asm("v_cvt_pk_bf16_f32 %0, %1, %2" : "=v"(r) : "v"(a), "v"(b));
  return r;
}
__device__ __forceinline__ uint16_t f2bf(float f){
  return (uint16_t)pk_bf16(f, f);
}

// async global->LDS, 16B per lane; lds base wave-uniform (HW adds lane*16)
__device__ __forceinline__ void gl2lds16(const uint16_t* g, uint16_t* l) {
  __builtin_amdgcn_global_load_lds((const __attribute__((address_space(1))) void*)g,
                                   (__attribute__((address_space(3))) void*)l, 16, 0, 0);
}

// ---------------- weight transpose + f32->bf16 convert (optional row-scale) ----
__global__ __launch_bounds__(256) void transpose_cvt(
    const float* __restrict__ src, uint16_t* __restrict__ dst, int K, int N,
    const float* __restrict__ scale)
{
  __shared__ float tile[32][33];
  int n0 = blockIdx.x * 32, k0 = blockIdx.y * 32;
  int tx = threadIdx.x & 31, ty = threadIdx.x >> 5;
  #pragma unroll
  for (int i = 0; i < 4; i++) {
    int k = k0 + ty + 8*i;
    float v = src[(size_t)k * N + n0 + tx];
    if (scale) v *= scale[k];
    tile[ty + 8*i][tx] = v;
  }
  __syncthreads();
  #pragma unroll
  for (int i = 0; i < 4; i++)
    dst[(size_t)(n0 + ty + 8*i) * K + k0 + tx] = f2bf(tile[tx][ty + 8*i]);
}

// ---------------- LN1 fold precompute: c1[j]=sum_k g1[k]Wfp[k][j]; b1p=be1@Wfp+bfp ----
__global__ __launch_bounds__(256) void fold_fp(
    const float* __restrict__ Wfp, const float* __restrict__ g1,
    const float* __restrict__ be1, const float* __restrict__ bfp,
    float* __restrict__ c1, float* __restrict__ b1p)
{
  int j = threadIdx.x;
  float c = 0.f, b = 0.f;
  for (int k = 0; k < 256; k++) {
    float w = Wfp[k * 256 + j];
    c += g1[k] * w;
    b += be1[k] * w;
  }
  c1[j] = c;
  b1p[j] = b + bfp[j];
}

// ---------------- fused mid: qkv GEMM + attn(6x6) + LN1(folded) + fp GEMM + LN2 -> F ----
// 512 threads (8 waves), 48 rows; LDS overlay: h lives in dead K|V region of qs.
#define LX 136
#define LQ 392

__global__ __launch_bounds__(512, 4) void fused_mid(
    const float* __restrict__ X, const uint16_t* __restrict__ WqkvT,
    const float* __restrict__ bqkv, const uint16_t* __restrict__ Wfp2T,
    const float* __restrict__ c1, const float* __restrict__ b1p,
    const float* __restrict__ g2, const float* __restrict__ be2,
    uint16_t* __restrict__ F)
{
  __shared__ uint16_t xs[48 * LX];    // 12.75 KB  x bf16
  __shared__ uint16_t qs[48 * LQ];    // 36.75 KB
  __shared__ float    sb[8 * 36];
  __shared__ float    smu[48], srs[48];
  int t = threadIdx.x;
  int lane = t & 63, wave = t >> 6;   // 8 waves
  int lr = lane & 15, lh = lane >> 4;
  size_t r0 = (size_t)blockIdx.x * 48;

  // ---- phase 1: stage x -> xs (bf16, packed cvt) ----
  for (int i = t; i < 768; i += 512) {
    int row = i >> 4, c = (i & 15) * 8;
    const float* g = X + (r0 + row) * 128 + c;
    f32x4 v0 = *(const f32x4*)g, v1 = *(const f32x4*)(g + 4);
    u32x4 o;
    o[0] = pk_bf16(v0[0], v0[1]); o[1] = pk_bf16(v0[2], v0[3]);
    o[2] = pk_bf16(v1[0], v1[1]); o[3] = pk_bf16(v1[2], v1[3]);
    *(u32x4*)(xs + row * LX + c) = o;
  }
  __syncthreads();

  // ---- phase 2: qkv GEMM (48x384), 8 waves x 48 cols ----
  {
    f32x4 acc[3][3] = {};
    #pragma unroll
    for (int k0 = 0; k0 < 128; k0 += 32) {
      bf16x8 af[3], bw[3];
      #pragma unroll
      for (int i = 0; i < 3; i++)
        af[i] = *(const bf16x8*)(xs + (i*16 + lr) * LX + k0 + lh*8);
      #pragma unroll
      for (int j = 0; j < 3; j++)
        bw[j] = *(const bf16x8*)(WqkvT + (size_t)(wave*48 + j*16 + lr) * 128 + k0 + lh*8);
      #pragma unroll
      for (int i = 0; i < 3; i++)
        #pragma unroll
        for (int j = 0; j < 3; j++)
          acc[i][j] = __builtin_amdgcn_mfma_f32_16x16x32_bf16(af[i], bw[j], acc[i][j], 0, 0, 0);
    }
    #pragma unroll
    for (int i = 0; i < 3; i++)
      #pragma unroll
      for (int j = 0; j < 3; j++) {
        int col = wave*48 + j*16 + lr;
        float bv = bqkv[col];
        #pragma unroll
        for (int r = 0; r < 4; r++)
          qs[(i*16 + lh*4 + r) * LQ + col] = f2bf(acc[i][j][r] + bv);
      }
  }
  __syncthreads();

  // ---- phase 3: S[b][q][k] = Q . K  (b128 LDS reads: 32 per dot) ----
  for (int i = t; i < 288; i += 512) {
    int b = i / 36, q = (i / 6) % 6, k = i % 6;
    const uint16_t* Qr = qs + (b*6 + q) * LQ;
    const uint16_t* Kr = qs + (b*6 + k) * LQ + 128;
    float s = 0.f;
    #pragma unroll
    for (int d = 0; d < 16; d++) {
      u32x4 qv = *(const u32x4*)(Qr + d*8);
      u32x4 kv = *(const u32x4*)(Kr + d*8);
      #pragma unroll
      for (int j = 0; j < 4; j++) {
        s += u2f(qv[j] << 16) * u2f(kv[j] << 16)
           + u2f(qv[j] & 0xFFFF0000u) * u2f(kv[j] & 0xFFFF0000u);
      }
    }
    sb[i] = s;
  }
  __syncthreads();

  // ---- phase 4: ar = S @ V -> dead Q region (u32x2 reads/writes) ----
  for (int i = t; i < 1536; i += 512) {
    int r = i >> 5, dp = (i & 31) * 2;   // dp = u32 pair index (4 bf16)
    int b = r / 6;
    const float* sr = sb + b*36 + (r - b*6)*6;
    float a0 = 0.f, a1 = 0.f, a2 = 0.f, a3 = 0.f;
    #pragma unroll
    for (int k = 0; k < 6; k++) {
      u32x2 vu = *(const u32x2*)(qs + (b*6 + k)*LQ + 256 + dp*2);
      float sk = sr[k];
      a0 += sk * u2f(vu[0] << 16);
      a1 += sk * u2f(vu[0] & 0xFFFF0000u);
      a2 += sk * u2f(vu[1] << 16);
      a3 += sk * u2f(vu[1] & 0xFFFF0000u);
    }
    u32x2 o; o[0] = pk_bf16(a0, a1); o[1] = pk_bf16(a2, a3);
    *(u32x2*)((uint32_t*)(qs + r*LQ) + dp) = o;
  }
  __syncthreads();

  // ---- phase 5: [t<192] LN1 stats; ALL: fp GEMM (8 waves x 32 cols) ----
  if (t < 192) {
    int r = t >> 2, p = t & 3;
    const uint32_t* src = (p < 2) ? (const uint32_t*)(xs + r*LX + p*64)
                                  : (const uint32_t*)(qs + r*LQ + (p - 2)*64);
    float s1 = 0.f, s2 = 0.f;
    #pragma unroll 8
    for (int d = 0; d < 32; d++) {
      uint32_t u = src[d];
      float a = u2f(u << 16), b = u2f(u & 0xFFFF0000u);
      s1 += a + b; s2 += a*a + b*b;
    }
    s1 += __shfl_xor(s1, 1); s2 += __shfl_xor(s2, 1);
    s1 += __shfl_xor(s1, 2); s2 += __shfl_xor(s2, 2);
    float mu = s1 * (1.f/256.f);
    float var = s2 * (1.f/256.f) - mu*mu;
    if (p == 0) { smu[r] = mu; srs[r] = rsqrtf(var + 1e-5f); }
  }
  f32x4 acc2[3][2] = {};
  #pragma unroll
  for (int k0 = 0; k0 < 256; k0 += 32) {
    bf16x8 af[3], bw[2];
    #pragma unroll
    for (int i = 0; i < 3; i++) {
      const uint16_t* mrow = (k0 < 128) ? (xs + (i*16 + lr) * LX + k0)
                                        : (qs + (i*16 + lr) * LQ + (k0 - 128));
      af[i] = *(const bf16x8*)(mrow + lh*8);
    }
    #pragma unroll
    for (int j = 0; j < 2; j++)
      bw[j] = *(const bf16x8*)(Wfp2T + (size_t)(wave*32 + j*16 + lr) * 256 + k0 + lh*8);
    #pragma unroll
    for (int i = 0; i < 3; i++)
      #pragma unroll
      for (int j = 0; j < 2; j++)
        acc2[i][j] = __builtin_amdgcn_mfma_f32_16x16x32_bf16(af[i], bw[j], acc2[i][j], 0, 0, 0);
  }
  __syncthreads();

  // ---- phase 6: h = rs1*(G - mu1*c1[col]) + b1p[col] -> qs[.,128+col] ----
  #pragma unroll
  for (int i = 0; i < 3; i++)
    #pragma unroll
    for (int j = 0; j < 2; j++) {
      int col = wave*32 + j*16 + lr;
      float c1v = c1[col], b1v = b1p[col];
      #pragma unroll
      for (int r = 0; r < 4; r++) {
        int row = i*16 + lh*4 + r;
        float h = srs[row] * (acc2[i][j][r] - smu[row] * c1v) + b1v;
        qs[row * LQ + 128 + col] = f2bf(h);
      }
    }
  __syncthreads();

  // ---- phase 7: LN2 stats over [h(256) | x(128) | ar(128)] ----
  if (t < 192) {
    int r = t >> 2, p = t & 3;
    const uint32_t* src = (p < 2) ? (const uint32_t*)(qs + r*LQ + 128 + p*128)
                        : (p == 2) ? (const uint32_t*)(xs + r*LX)
                                   : (const uint32_t*)(qs + r*LQ);
    float s1 = 0.f, s2 = 0.f;
    #pragma unroll 8
    for (int d = 0; d < 64; d++) {
      uint32_t u = src[d];
      float a = u2f(u << 16), b = u2f(u & 0xFFFF0000u);
      s1 += a + b; s2 += a*a + b*b;
    }
    s1 += __shfl_xor(s1, 1); s2 += __shfl_xor(s2, 1);
    s1 += __shfl_xor(s1, 2); s2 += __shfl_xor(s2, 2);
    float mu = s1 * (1.f/512.f);
    float var = s2 * (1.f/512.f) - mu*mu;
    if (p == 0) { smu[r] = mu; srs[r] = rsqrtf(var + 1e-5f); }
  }
  __syncthreads();

  // ---- phase 8: f = LN2([h|x|ar]) -> F (packed cvt) ----
  for (int i = t; i < 3072; i += 512) {
    int r = i >> 6, c0 = (i & 63) * 8;
    float mu = smu[r], rs = srs[r];
    const uint16_t* src = (c0 < 256) ? (qs + r*LQ + 128 + c0)
                        : (c0 < 384) ? (xs + r*LX + (c0 - 256))
                                     : (qs + r*LQ + (c0 - 384));
    bf16x8 v = *(const bf16x8*)src;
    f32x4 gv0 = *(const f32x4*)(g2 + c0), gv1 = *(const f32x4*)(g2 + c0 + 4);
    f32x4 bv0 = *(const f32x4*)(be2 + c0), bv1 = *(const f32x4*)(be2 + c0 + 4);
    float f[8];
    #pragma unroll
    for (int j = 0; j < 4; j++) {
      f[j]   = (bf2f((uint16_t)v[j])   - mu) * rs * gv0[j] + bv0[j];
      f[4+j] = (bf2f((uint16_t)v[4+j]) - mu) * rs * gv1[j] + bv1[j];
    }
    u32x4 o;
    o[0] = pk_bf16(f[0], f[1]); o[1] = pk_bf16(f[2], f[3]);
    o[2] = pk_bf16(f[4], f[5]); o[3] = pk_bf16(f[6], f[7]);
    *(u32x4*)(F + (r0 + r) * 512 + c0) = o;
  }
}

// ---------------- K4: out = relu(f @ W_s + b_s) ----------------
// 256x256, 1024 threads = 16 waves (4m x 4n), BK=64, 2-slot dbuf (128KB),
// full-drain gate (48 gates), per-wave 64x64 output (acc[4][4]).
// 4 waves/SIMD -> implicit wave-level LDS/MFMA overlap (m114 mechanism).
// Row-XOR chunk swizzle (conflict-free, verified R14).
__global__ __launch_bounds__(1024, 4) void out_gemm(
    const uint16_t* __restrict__ F, const uint16_t* __restrict__ WsT,
    const float* __restrict__ b_s, float* __restrict__ OUT)
{
  __shared__ uint16_t lds[2][2][256*64];   // 128 KB: [slot][A/B][row*64 + ch*8]
  int t = threadIdx.x;
  int lane = t & 63, wave = t >> 6;        // 16 waves
  int wm = wave >> 2, wn = wave & 3;       // 4m x 4n wave grid
  int lr = lane & 15, lh = lane >> 4;

  int bid = blockIdx.x;
  int swz = (bid & 7) * 64 + (bid >> 3);
  size_t m0 = (size_t)(swz >> 2) * 256;
  int n0 = (swz & 3) * 256;

  // staging: per issue 1024 threads cover 128 rows x 64 cols; thread row = t>>3,
  // store chunk = t&7 (linear LDS dest = base + wave*512 elems), global source
  // chunk pre-swizzled gch = (t&7) ^ (row&7) so LDS holds ch' = ch ^ (row&7).
  int srow = t >> 3;                       // 0..127
  int gch  = (t & 7) ^ ((t >> 3) & 7);
  const uint16_t* Ag = F   + (m0 + srow) * 3072 + gch * 8;
  const uint16_t* Bg = WsT + (size_t)(n0 + srow) * 3072 + gch * 8;

#define STAGE(s, tt) do {                                                    \
    int kk0 = (tt) * 64;                                                     \
    uint16_t* la = &lds[s][0][0];                                            \
    uint16_t* lb = &lds[s][1][0];                                            \
    gl2lds16(Ag + kk0,                    la + wave*512);                    \
    gl2lds16(Ag + (size_t)128*3072 + kk0, la + 8192 + wave*512);             \
    gl2lds16(Bg + kk0,                    lb + wave*512);                    \
    gl2lds16(Bg + (size_t)128*3072 + kk0, lb + 8192 + wave*512);             \
  } while(0)

  f32x4 acc[4][4] = {};
  int swlo = lr & 7;                       // row&7 for all fragment rows

#define COMPUTE(s) do {                                                      \
    const uint16_t* As_ = &lds[s][0][0];                                     \
    const uint16_t* Bs_ = &lds[s][1][0];                                     \
    _Pragma("unroll")                                                        \
    for (int ks = 0; ks < 2; ks++) {                                         \
      int ch = ((ks*4 + lh) ^ swlo) * 8;                                     \
      bf16x8 af[4], bfr[4];                                                  \
      _Pragma("unroll")                                                      \
      for (int i = 0; i < 4; i++)                                            \
        af[i]  = *(const bf16x8*)(As_ + (wm*64 + i*16 + lr)*64 + ch);        \
      _Pragma("unroll")                                                      \
      for (int j = 0; j < 4; j++)                                            \
        bfr[j] = *(const bf16x8*)(Bs_ + (wn*64 + j*16 + lr)*64 + ch);        \
      __builtin_amdgcn_s_setprio(1);                                         \
      _Pragma("unroll")                                                      \
      for (int i = 0; i < 4; i++)                                            \
        _Pragma("unroll")                                                    \
        for (int j = 0; j < 4; j++)                                          \
          acc[i][j] = __builtin_amdgcn_mfma_f32_16x16x32_bf16(af[i], bfr[j], \
                                                              acc[i][j],0,0,0);\
      __builtin_amdgcn_s_setprio(0);                                         \
    }                                                                        \
  } while(0)

  STAGE(0, 0);
  for (int tt = 0; tt < 48; ++tt) {
    int cur = tt & 1;
    asm volatile("s_waitcnt vmcnt(0)" ::: "memory");   // tile tt landed
    __builtin_amdgcn_s_barrier();                      // slot cur^1 readers done
    asm volatile("" ::: "memory");
    if (tt < 47) STAGE(cur ^ 1, tt + 1);               // overwrite freed slot
    COMPUTE(cur);
  }

#undef STAGE
#undef COMPUTE

  #pragma unroll
  for (int i = 0; i < 4; i++)
    #pragma unroll
    for (int j = 0; j < 4; j++) {
      int col = n0 + wn*64 + j*16 + lr;
      float bv = b_s[col];
      #pragma unroll
      for (int r = 0; r < 4; r++) {
        size_t row = m0 + wm*64 + i*16 + lh*4 + r;
        OUT[row * 1024 + col] = fmaxf(acc[i][j][r] + bv, 0.f);
      }
    }
}

extern "C" void kernel_launch(void* const* d_in, const int* in_sizes, int n_in,
                              void* d_out, int out_size, void* d_ws, size_t ws_size,
                              hipStream_t stream) {
  const float* x    = (const float*)d_in[0];
  const float* Wqkv = (const float*)d_in[1];
  const float* bqkv = (const float*)d_in[2];
  const float* g1   = (const float*)d_in[3];
  const float* be1  = (const float*)d_in[4];
  const float* Wfp  = (const float*)d_in[5];
  const float* bfp  = (const float*)d_in[6];
  const float* g2   = (const float*)d_in[7];
  const float* be2  = (const float*)d_in[8];
  const float* Ws   = (const float*)d_in[9];
  const float* bs   = (const float*)d_in[10];
  float* out = (float*)d_out;

  uint8_t* ws = (uint8_t*)d_ws;
  uint16_t* F     = (uint16_t*)(ws);                  // 32768x3072 bf16
  uint16_t* WqkvT = (uint16_t*)(ws + 201326592ull);   // 384x128
  uint16_t* Wfp2T = (uint16_t*)(ws + 201424896ull);   // 256x256 (g1-folded)
  uint16_t* WsT   = (uint16_t*)(ws + 201555968ull);   // 1024x3072
  float*    c1    = (float*)(ws + 207847424ull);      // 256 f32
  float*    b1p   = (float*)(ws + 207848448ull);      // 256 f32

  transpose_cvt<<<dim3(12, 4), 256, 0, stream>>>(Wqkv, WqkvT, 128, 384, nullptr);
  transpose_cvt<<<dim3(8, 8), 256, 0, stream>>>(Wfp, Wfp2T, 256, 256, g1);
  transpose_cvt<<<dim3(32, 96), 256, 0, stream>>>(Ws, WsT, 3072, 1024, nullptr);
  fold_fp<<<dim3(1), 256, 0, stream>>>(Wfp, g1, be1, bfp, c1, b1p);
  fused_mid<<<dim3(4096), 512, 0, stream>>>(x, WqkvT, bqkv, Wfp2T, c1, b1p,
                                            g2, be2, F);
  out_gemm<<<dim3(512), 1024, 0, stream>>>(F, WsT, bs, out);
}